// Round 2
// baseline (1048.524 us; speedup 1.0000x reference)
//
#include <hip/hip_runtime.h>

// B-spline dense scatter: out[row, col] = value_k(xs[row]) for
// col == floor(xs[row]) + k (k in 0..3), else 0.  Output 131072 x 2048 f32
// = 1.07 GB -> pure HBM-write-bound stream.
//
// R1 lesson: 131072 tiny blocks (2 stores/thread) were dispatch-rate-bound
// at 1.06 TB/s. Persistent grid (2048 blocks, 64 contiguous rows each,
// grid-stride over rows) amortizes per-block overhead; fillBufferAligned
// proves ~6.2 TB/s is reachable on this buffer with this shape.

__global__ __launch_bounds__(256) void bspline_rows_kernel(
    const float* __restrict__ xs,
    const float* __restrict__ B,   // [4][4] ascending-power coeffs
    float* __restrict__ out,
    int n_samples,
    int n_knots) {
    // Contiguous row chunk per block: block b owns rows [b*rpb, (b+1)*rpb).
    const int rpb = (n_samples + gridDim.x - 1) / gridDim.x;
    const int row_lo = blockIdx.x * rpb;
    const int row_hi = min(row_lo + rpb, n_samples);

    const int tid = threadIdx.x;
    const int nvec = n_knots >> 2;            // float4s per row (512)

    for (int r = row_lo; r < row_hi; ++r) {
        const float x = xs[r];                // broadcast load, L1-hit
        const float fif = floorf(x);
        const int fi = (int)fif;
        float* outrow = out + (size_t)r * (size_t)n_knots;

        for (int v = tid; v < nvec; v += 256) {
            const int c = v << 2;
            float4 w = make_float4(0.0f, 0.0f, 0.0f, 0.0f);
            if (c + 3 >= fi && c <= fi + 3) { // <=2 threads/row take this
                const float frac = x - fif;
                float t;
                t = frac + 3.0f;
                const float v0 = ((B[3]*t + B[2])*t + B[1])*t + B[0];
                t = frac + 2.0f;
                const float v1 = ((B[7]*t + B[6])*t + B[5])*t + B[4];
                t = frac + 1.0f;
                const float v2 = ((B[11]*t + B[10])*t + B[9])*t + B[8];
                t = frac;
                const float v3 = ((B[15]*t + B[14])*t + B[13])*t + B[12];
                float* wp = (float*)&w;
                #pragma unroll
                for (int j = 0; j < 4; ++j) {
                    const int k = (c + j) - fi;
                    if (k == 0) wp[j] = v0;
                    else if (k == 1) wp[j] = v1;
                    else if (k == 2) wp[j] = v2;
                    else if (k == 3) wp[j] = v3;
                }
            }
            *(float4*)(outrow + c) = w;
        }
    }
}

extern "C" void kernel_launch(void* const* d_in, const int* in_sizes, int n_in,
                              void* d_out, int out_size, void* d_ws, size_t ws_size,
                              hipStream_t stream) {
    const float* xs = (const float*)d_in[0];
    const float* B  = (const float*)d_in[1];   // 16 floats (q=3)
    float* out = (float*)d_out;

    const int n_samples = in_sizes[0];                 // 131072
    const int n_knots   = out_size / n_samples;        // 2048

    // 2048 blocks x 256 thr = 8192 waves = 32 waves/CU on 256 CUs.
    int grid = 2048;
    if (grid > n_samples) grid = n_samples;
    bspline_rows_kernel<<<grid, 256, 0, stream>>>(xs, B, out, n_samples, n_knots);
}

// Round 3
// 1045.540 us; speedup vs baseline: 1.0029x; 1.0029x over previous
//
#include <hip/hip_runtime.h>

// B-spline dense scatter: out[row, col] = value_k(xs[row]) for
// col == floor(xs[row]) + k (k in 0..3), else 0.  Output 131072 x 2048 f32
// = 1.07 GB -> pure HBM-write-bound stream.
//
// Evidence trail:
//  R1: 131072 blocks x 1 row  -> dur_us 1011 (kernel ~148 us after ~863 us
//      of in-stream harness poison fills; kernel absent from top-5 profile
//      dispatches, all fills at ~690 us, so kernel < 682 us).
//  R2: 2048 persistent blocks x 64-row serial loop -> 1048 (kernel ~185 us).
//      Persistent grid REGRESSED -> dispatch overhead was not the bottleneck.
//  R3: middle ground: 4 rows/block fully unrolled, 32768 blocks; one
//      unsigned-range compare per store; keep L2/LLC write path (no nt
//      stores -- LLC absorbs ~256MB of the 1.07GB, effective BW > HBM peak).

constexpr int RPB = 4;  // rows per block, fully unrolled

__global__ __launch_bounds__(256) void bspline_r4_kernel(
    const float* __restrict__ xs,
    const float* __restrict__ B,   // [4][4] ascending-power coeffs
    float* __restrict__ out,
    int n_samples,
    int n_knots) {
    const int row0 = blockIdx.x * RPB;
    const int tid = threadIdx.x;
    const int nvec = n_knots >> 2;           // float4s per row (512)

    #pragma unroll
    for (int rr = 0; rr < RPB; ++rr) {
        const int r = row0 + rr;
        if (r >= n_samples) break;           // never taken for 131072/4
        const float x = xs[r];               // block-uniform -> s_load
        const float fif = floorf(x);
        const int fi = (int)fif;
        float* outrow = out + (size_t)r * (size_t)n_knots;

        for (int v = tid; v < nvec; v += 256) {   // 2 iters at n_knots=2048
            const int c = v << 2;
            float4 w = make_float4(0.0f, 0.0f, 0.0f, 0.0f);
            // store [c, c+3] overlaps nonzero window [fi, fi+3]
            // iff c in [fi-3, fi+3]
            if ((unsigned)(c - fi + 3) <= 6u) {  // <=2 threads per row
                const float frac = x - fif;
                float t;
                t = frac + 3.0f;
                const float v0 = ((B[3]*t + B[2])*t + B[1])*t + B[0];
                t = frac + 2.0f;
                const float v1 = ((B[7]*t + B[6])*t + B[5])*t + B[4];
                t = frac + 1.0f;
                const float v2 = ((B[11]*t + B[10])*t + B[9])*t + B[8];
                t = frac;
                const float v3 = ((B[15]*t + B[14])*t + B[13])*t + B[12];
                float* wp = (float*)&w;
                #pragma unroll
                for (int j = 0; j < 4; ++j) {
                    const int k = (c + j) - fi;
                    if (k == 0) wp[j] = v0;
                    else if (k == 1) wp[j] = v1;
                    else if (k == 2) wp[j] = v2;
                    else if (k == 3) wp[j] = v3;
                }
            }
            *(float4*)(outrow + c) = w;
        }
    }
}

extern "C" void kernel_launch(void* const* d_in, const int* in_sizes, int n_in,
                              void* d_out, int out_size, void* d_ws, size_t ws_size,
                              hipStream_t stream) {
    const float* xs = (const float*)d_in[0];
    const float* B  = (const float*)d_in[1];   // 16 floats (q=3)
    float* out = (float*)d_out;

    const int n_samples = in_sizes[0];                 // 131072
    const int n_knots   = out_size / n_samples;        // 2048

    const int grid = (n_samples + RPB - 1) / RPB;      // 32768
    bspline_r4_kernel<<<grid, 256, 0, stream>>>(xs, B, out, n_samples, n_knots);
}

// Round 4
// 1014.778 us; speedup vs baseline: 1.0333x; 1.0303x over previous
//
#include <hip/hip_runtime.h>

// B-spline dense scatter: out[row, col] = value_k(xs[row]) when
// col == floor(xs[row]) + k (k in 0..3), else 0.
// value_k = sum_p x_loc^p * B[k][p], x_loc = frac(x) + (3 - k).
// Output is 131072 x 2048 f32 = 1.07 GB -> pure HBM-write-bound stream.
//
// Evidence trail (dur_us includes ~863 us of fixed in-stream harness poison
// fills; kernel never appears in top-5 dispatches, so kernel << 682 us):
//  R1: 131072 blocks x 1 row, 2 float4 stores/thread -> 1011 (kernel ~148 us,
//      ~7.2 TB/s effective incl. LLC write absorption -- above the 6.2 TB/s
//      fillBuffer rate on the same stream).
//  R2: 2048 persistent blocks, 64-row serial loop     -> 1048 (kernel ~185).
//  R3: 32768 blocks x 4 rows unrolled                 -> 1045 (kernel ~182).
//  Conclusion: the 1-row/block shape wins (max independent stores in flight,
//  no serial row dependence). Reverting to R1 verbatim. No byte-reduction
//  lever exists: output is dense and re-poisoned before every call; nt
//  stores would forfeit the LLC absorption that puts us above fill-rate.

__global__ __launch_bounds__(256) void bspline_row_kernel(
    const float* __restrict__ xs,
    const float* __restrict__ B,   // [4][4] ascending-power coeffs
    float* __restrict__ out,
    int n_knots) {
    const int row = blockIdx.x;
    const float x = xs[row];                 // broadcast load (L1 hit after lane 0)
    const float fif = floorf(x);
    const int fi = (int)fif;
    const float frac = x - fif;

    // Cubic values for the 4 overlapping basis polynomials (Horner).
    // B pointer is uniform + constant indices -> compiler emits s_load.
    float v0, v1, v2, v3;
    {
        float t;
        t = frac + 3.0f; v0 = ((B[0*4+3]*t + B[0*4+2])*t + B[0*4+1])*t + B[0*4+0];
        t = frac + 2.0f; v1 = ((B[1*4+3]*t + B[1*4+2])*t + B[1*4+1])*t + B[1*4+0];
        t = frac + 1.0f; v2 = ((B[2*4+3]*t + B[2*4+2])*t + B[2*4+1])*t + B[2*4+0];
        t = frac + 0.0f; v3 = ((B[3*4+3]*t + B[3*4+2])*t + B[3*4+1])*t + B[3*4+0];
    }

    float* outrow = out + (size_t)row * (size_t)n_knots;

    // Vectorized zero-stream with value insertion where the 4-wide span
    // [c, c+3] overlaps the nonzero window [fi, fi+3].
    const int nvec = n_knots & ~3;
    for (int c = threadIdx.x * 4; c < nvec; c += blockDim.x * 4) {
        float4 w = make_float4(0.0f, 0.0f, 0.0f, 0.0f);
        if (c + 3 >= fi && c <= fi + 3) {   // rare divergent path (1-2 threads/row)
            float* wp = (float*)&w;
            #pragma unroll
            for (int j = 0; j < 4; ++j) {
                const int k = (c + j) - fi;
                float val = 0.0f;
                if (k == 0) val = v0;
                else if (k == 1) val = v1;
                else if (k == 2) val = v2;
                else if (k == 3) val = v3;
                wp[j] = val;
            }
        }
        *(float4*)(outrow + c) = w;
    }
    // Scalar tail if n_knots % 4 != 0 (not hit for n=2048, kept for generality).
    for (int c = nvec + (int)threadIdx.x; c < n_knots; c += (int)blockDim.x) {
        const int k = c - fi;
        float val = 0.0f;
        if (k == 0) val = v0;
        else if (k == 1) val = v1;
        else if (k == 2) val = v2;
        else if (k == 3) val = v3;
        outrow[c] = val;
    }
}

extern "C" void kernel_launch(void* const* d_in, const int* in_sizes, int n_in,
                              void* d_out, int out_size, void* d_ws, size_t ws_size,
                              hipStream_t stream) {
    const float* xs = (const float*)d_in[0];
    const float* B  = (const float*)d_in[1];   // 16 floats (q=3)
    float* out = (float*)d_out;

    const int n_samples = in_sizes[0];                 // 131072
    const int n_knots   = out_size / n_samples;        // 2048

    bspline_row_kernel<<<n_samples, 256, 0, stream>>>(xs, B, out, n_knots);
}